// Round 1
// baseline (830.585 us; speedup 1.0000x reference)
//
#include <hip/hip_runtime.h>

#define TPB 64            // tokens per block
#define DIM 256
#define KCODES 1024
#define LEVELS 4
#define CHUNK 64
#define NCHUNK (KCODES / CHUNK)   // 16
#define RS 264                    // padded LDS row stride in halves (528 B: 16B-aligned, 2-way bank alias only)
#define NTOK 65536
#define NELEM (NTOK * DIM)        // 16777216

typedef _Float16 h8 __attribute__((ext_vector_type(8)));
typedef _Float16 h4 __attribute__((ext_vector_type(4)));
typedef float f4 __attribute__((ext_vector_type(4)));

// Phase 0: convert codebooks fp32 -> fp16 and compute 0.5*||e||^2 per code row.
// 4096 rows total; one wave per row, 4 rows per block -> 1024 blocks.
__global__ __launch_bounds__(256) void rvq_prep(const float* __restrict__ cb,
                                                _Float16* __restrict__ cb16,
                                                float* __restrict__ e2h) {
  const int row = blockIdx.x * 4 + (threadIdx.x >> 6);
  const int lane = threadIdx.x & 63;
  const float* src = cb + (size_t)row * DIM + lane * 4;
  f4 v = *(const f4*)src;
  h4 hv;
  hv[0] = (_Float16)v[0]; hv[1] = (_Float16)v[1];
  hv[2] = (_Float16)v[2]; hv[3] = (_Float16)v[3];
  *(h4*)(cb16 + (size_t)row * DIM + lane * 4) = hv;
  float s = v[0]*v[0] + v[1]*v[1] + v[2]*v[2] + v[3]*v[3];
  #pragma unroll
  for (int off = 32; off; off >>= 1) s += __shfl_xor(s, off, 64);
  if (lane == 0) e2h[row] = 0.5f * s;
}

// Main fused RVQ kernel. Block = 256 threads = 4 waves; wave owns 16 tokens.
// Lane layout: token = wave*16 + (lane&15); dims handled = {k*32 + quad*8 + j}.
// This matches the mfma_f32_16x16x32_f16 A-fragment (A[m=lane&15][k=quad*8+j]),
// so A-frags are built in-lane from the fp32 residual registers (no LDS for A).
__global__ __launch_bounds__(256, 2) void rvq_main(
    const float* __restrict__ x, const float* __restrict__ cb32,
    const _Float16* __restrict__ cb16, const float* __restrict__ e2h,
    float* __restrict__ out) {
  __shared__ _Float16 clds[CHUNK][RS];   // 33792 B codebook chunk (codes x D, padded)
  __shared__ float e2_lds[KCODES];       // 4096 B: current level's 0.5*||e||^2
  __shared__ int idx_sh[TPB];
  __shared__ float csum_sh[4];

  const int tid = threadIdx.x;
  const int wave = tid >> 6;
  const int lane = tid & 63;
  const int col = lane & 15;
  const int quad = lane >> 4;

  const int t_local = wave * 16 + col;
  const size_t t_global = (size_t)blockIdx.x * TPB + t_local;
  const float* xrow = x + t_global * DIM;

  // fp32 residual in registers + fp16 A-fragments
  float res[64];
  h8 af[8];
  #pragma unroll
  for (int k = 0; k < 8; ++k) {
    f4 a = *(const f4*)(xrow + k * 32 + quad * 8);
    f4 b = *(const f4*)(xrow + k * 32 + quad * 8 + 4);
    #pragma unroll
    for (int j = 0; j < 4; ++j) { res[k*8 + j] = a[j]; res[k*8 + 4 + j] = b[j]; }
    h8 h;
    #pragma unroll
    for (int j = 0; j < 4; ++j) { h[j] = (_Float16)a[j]; h[4 + j] = (_Float16)b[j]; }
    af[k] = h;
  }

  float commit_acc = 0.0f;

  // staging: thread covers row (tid>>2) of the chunk, col group (tid&3)*64 halves
  const int srow = tid >> 2;
  const int sg = tid & 3;
  uint4 st[8];

  for (int lvl = 0; lvl < LEVELS; ++lvl) {
    __syncthreads();  // all waves done with previous level's compare/gather
    // stage this level's e2 table (visible after first chunk barrier)
    *(f4*)&e2_lds[tid * 4] = *(const f4*)(e2h + (lvl << 10) + tid * 4);

    // prefetch chunk 0 into registers
    {
      const uint4* src = (const uint4*)(cb16 + (((size_t)(lvl << 10) + srow) * DIM)) + sg * 8;
      #pragma unroll
      for (int j = 0; j < 8; ++j) st[j] = src[j];
    }

    float bv[16];
    int bi[16];
    #pragma unroll
    for (int s = 0; s < 16; ++s) { bv[s] = -3.4e38f; bi[s] = 0; }

    for (int c = 0; c < NCHUNK; ++c) {
      __syncthreads();  // clds free
      {
        uint4* dst = (uint4*)&clds[srow][sg * 64];
        #pragma unroll
        for (int j = 0; j < 8; ++j) dst[j] = st[j];
      }
      if (c + 1 < NCHUNK) {  // register-prefetch next chunk; loads fly during MFMA phase
        const uint4* src =
            (const uint4*)(cb16 + (((size_t)(lvl << 10) + (c + 1) * CHUNK + srow) * DIM)) + sg * 8;
        #pragma unroll
        for (int j = 0; j < 8; ++j) st[j] = src[j];
      }
      __syncthreads();  // clds ready

      const int cbase = c * CHUNK;
      #pragma unroll
      for (int nt = 0; nt < 4; ++nt) {
        f4 acc = {0.0f, 0.0f, 0.0f, 0.0f};
        const _Float16* bb = &clds[nt * 16 + col][quad * 8];
        #pragma unroll
        for (int k = 0; k < 8; ++k) {
          h8 b = *(const h8*)(bb + k * 32);
          acc = __builtin_amdgcn_mfma_f32_16x16x32_f16(af[k], b, acc, 0, 0, 0);
        }
        const int code = cbase + nt * 16 + col;
        const float e2v = e2_lds[code];
        #pragma unroll
        for (int i = 0; i < 4; ++i) {  // D[m=quad*4+i][n=col]: token slot = quad*4+i
          float val = acc[i] - e2v;
          const int s = nt * 4 + i;
          if (val > bv[s]) { bv[s] = val; bi[s] = code; }
        }
      }
    }

    // argmin finalize: in-lane over nt, then xor-shuffle over the 16 lanes of the quad
    float rv[4]; int ri[4];
    #pragma unroll
    for (int i = 0; i < 4; ++i) {
      rv[i] = bv[i]; ri[i] = bi[i];
      #pragma unroll
      for (int nt = 1; nt < 4; ++nt) {
        float v = bv[nt * 4 + i]; int ix = bi[nt * 4 + i];
        if (v > rv[i] || (v == rv[i] && ix < ri[i])) { rv[i] = v; ri[i] = ix; }
      }
      #pragma unroll
      for (int off = 1; off < 16; off <<= 1) {
        float ov = __shfl_xor(rv[i], off, 16);
        int oi = __shfl_xor(ri[i], off, 16);
        if (ov > rv[i] || (ov == rv[i] && oi < ri[i])) { rv[i] = ov; ri[i] = oi; }
      }
    }
    if (col == 0) {
      #pragma unroll
      for (int i = 0; i < 4; ++i) idx_sh[wave * 16 + quad * 4 + i] = ri[i];
    }
    __syncthreads();

    // gather q (fp32, exact), update residual + commit, rebuild A-frags
    const int qi = idx_sh[t_local];
    const float* qrow = cb32 + (((size_t)(lvl << 10) + qi)) * DIM;
    #pragma unroll
    for (int k = 0; k < 8; ++k) {
      f4 q0 = *(const f4*)(qrow + k * 32 + quad * 8);
      f4 q1 = *(const f4*)(qrow + k * 32 + quad * 8 + 4);
      h8 h;
      #pragma unroll
      for (int j = 0; j < 4; ++j) {
        float r0 = res[k*8 + j] - q0[j];
        res[k*8 + j] = r0; commit_acc += r0 * r0; h[j] = (_Float16)r0;
        float r1 = res[k*8 + 4 + j] - q1[j];
        res[k*8 + 4 + j] = r1; commit_acc += r1 * r1; h[4 + j] = (_Float16)r1;
      }
      af[k] = h;
    }
  }

  // epilogue: y = x - r_final  (== sum of quantized codes, fp32-exact)
  float* orow = out + t_global * DIM;
  #pragma unroll
  for (int k = 0; k < 8; ++k) {
    f4 xa = *(const f4*)(xrow + k * 32 + quad * 8);
    f4 xb = *(const f4*)(xrow + k * 32 + quad * 8 + 4);
    f4 y0, y1;
    #pragma unroll
    for (int j = 0; j < 4; ++j) { y0[j] = xa[j] - res[k*8 + j]; y1[j] = xb[j] - res[k*8 + 4 + j]; }
    *(f4*)(orow + k * 32 + quad * 8) = y0;
    *(f4*)(orow + k * 32 + quad * 8 + 4) = y1;
  }

  // commit: wave reduce -> block reduce -> one atomic per block
  #pragma unroll
  for (int off = 32; off; off >>= 1) commit_acc += __shfl_xor(commit_acc, off, 64);
  if (lane == 0) csum_sh[wave] = commit_acc;
  __syncthreads();
  if (tid == 0) {
    float s = csum_sh[0] + csum_sh[1] + csum_sh[2] + csum_sh[3];
    atomicAdd(out + NELEM, s * (0.25f / 16777216.0f));  // BETA / (N*D), summed over levels
  }
}

extern "C" void kernel_launch(void* const* d_in, const int* in_sizes, int n_in,
                              void* d_out, int out_size, void* d_ws, size_t ws_size,
                              hipStream_t stream) {
  const float* x = (const float*)d_in[0];
  const float* cb = (const float*)d_in[1];
  float* out = (float*)d_out;
  _Float16* cb16 = (_Float16*)d_ws;                                    // 2 MiB
  float* e2h = (float*)((char*)d_ws + (size_t)LEVELS * KCODES * DIM * sizeof(_Float16));  // 16 KiB

  rvq_prep<<<(LEVELS * KCODES) / 4, 256, 0, stream>>>(cb, cb16, e2h);
  hipMemsetAsync(out + NELEM, 0, sizeof(float), stream);               // zero commit accumulator
  rvq_main<<<NTOK / TPB, 256, 0, stream>>>(x, cb, cb16, e2h, out);
}

// Round 2
// 252.766 us; speedup vs baseline: 3.2860x; 3.2860x over previous
//
#include <hip/hip_runtime.h>

#define DIM 256
#define KCODES 1024
#define LEVELS 4
#define CHUNK 64
#define NCHUNK 16
#define TOKB 128                 // tokens per block (4 waves x 32)
#define NTOK 65536
#define NELEM (NTOK * DIM)

typedef _Float16 h8 __attribute__((ext_vector_type(8)));
typedef _Float16 h4 __attribute__((ext_vector_type(4)));
typedef float f4 __attribute__((ext_vector_type(4)));
typedef unsigned int u32;

__device__ __forceinline__ void gload16(const void* g, void* l) {
  __builtin_amdgcn_global_load_lds(
      (const __attribute__((address_space(1))) void*)g,
      (__attribute__((address_space(3))) void*)l, 16, 0, 0);
}

// Phase 0: cb fp32 -> fp16, and e2h = -0.5*||e||^2 per code row.
__global__ __launch_bounds__(256) void rvq_prep(const float* __restrict__ cb,
                                                _Float16* __restrict__ cb16,
                                                float* __restrict__ e2h) {
  const int row = blockIdx.x * 4 + (threadIdx.x >> 6);
  const int lane = threadIdx.x & 63;
  const float* src = cb + (size_t)row * DIM + lane * 4;
  f4 v = *(const f4*)src;
  h4 hv;
  hv[0] = (_Float16)v[0]; hv[1] = (_Float16)v[1];
  hv[2] = (_Float16)v[2]; hv[3] = (_Float16)v[3];
  *(h4*)(cb16 + (size_t)row * DIM + lane * 4) = hv;
  float s = v[0]*v[0] + v[1]*v[1] + v[2]*v[2] + v[3]*v[3];
  #pragma unroll
  for (int off = 32; off; off >>= 1) s += __shfl_xor(s, off, 64);
  if (lane == 0) e2h[row] = -0.5f * s;
}

// Main fused RVQ. Block = 256 thr = 4 waves; wave owns 32 tokens (2 m-tiles of
// 16). Residual lives ONLY as fp16 MFMA A-fragments (no fp32 res array -> no
// spills). Each ds_read_b128 B-fragment feeds 2 MFMAs (m-tile reuse).
// LDS chunk buffer is XOR-swizzled (pos = granule ^ (row&7)) so both the
// global_load_lds staging (lane-contiguous) and the B reads are bank-balanced.
__global__ __launch_bounds__(256, 2) void rvq_main(
    const float* __restrict__ x, const float* __restrict__ cb32,
    const _Float16* __restrict__ cb16, const float* __restrict__ e2h,
    float* __restrict__ out) {
  __shared__ __attribute__((aligned(16))) _Float16 clds[CHUNK * DIM];  // 32 KB
  __shared__ float e2_lds[KCODES];                                     // 4 KB
  __shared__ __attribute__((aligned(16))) int idx_hist[TOKB][4];       // 2 KB
  __shared__ float r2_sh[TOKB];
  __shared__ float csum_sh[4];

  const int tid = threadIdx.x;
  const int wave = tid >> 6, lane = tid & 63;
  const int col = lane & 15, quad = lane >> 4;
  const int Llo = lane & 31, Lhi = lane >> 5;

  // staging offsets: call i writes rows (wave*16+2i, +1); lane L fills row
  // position p=L&31 with global granule g = p ^ (row&7)  (XOR self-inverse)
  int soff[8], rdoff[8];
  #pragma unroll
  for (int i = 0; i < 8; ++i) {
    const int rl = wave * 16 + 2 * i + Lhi;
    soff[i] = rl * 512 + ((Llo ^ (rl & 7)) << 4);
  }
  // read offsets: B-frag granule g = kk*4+quad of row (nt*16+col)
  #pragma unroll
  for (int kk = 0; kk < 8; ++kk)
    rdoff[kk] = (((kk * 4 + quad) ^ (col & 7)) << 4);

  // ---- init: x -> fp16 A-frags + r2 partials ----
  h8 af[2][8];
  float r2p[2] = {0.f, 0.f};
  const size_t tok0 = (size_t)blockIdx.x * TOKB + wave * 32;
  #pragma unroll
  for (int mt = 0; mt < 2; ++mt) {
    const float* xr = x + (tok0 + mt * 16 + col) * DIM + quad * 8;
    #pragma unroll
    for (int kk = 0; kk < 8; ++kk) {
      f4 a = *(const f4*)(xr + kk * 32);
      f4 b = *(const f4*)(xr + kk * 32 + 4);
      h8 h;
      #pragma unroll
      for (int j = 0; j < 4; ++j) { h[j] = (_Float16)a[j]; h[4 + j] = (_Float16)b[j]; }
      af[mt][kk] = h;
      #pragma unroll
      for (int j = 0; j < 8; ++j) { float v = (float)h[j]; r2p[mt] += v * v; }
    }
  }

  float commit_acc = 0.f;
  const char* cb16b = (const char*)cb16;

  for (int lvl = 0; lvl < LEVELS; ++lvl) {
    // pre-update residual norms -> LDS (for commit identity)
    #pragma unroll
    for (int mt = 0; mt < 2; ++mt) {
      float s = r2p[mt];
      s += __shfl_xor(s, 16, 64);
      s += __shfl_xor(s, 32, 64);
      if (quad == 0) r2_sh[wave * 32 + mt * 16 + col] = s;
    }
    // this level's -0.5*||e||^2 table (prev readers done: post-idx barrier)
    *(f4*)&e2_lds[tid * 4] = *(const f4*)(e2h + (lvl << 10) + tid * 4);

    u32 best[2][4];
    #pragma unroll
    for (int mt = 0; mt < 2; ++mt)
      #pragma unroll
      for (int i = 0; i < 4; ++i) best[mt][i] = 0u;

    const size_t lvlbase = ((size_t)lvl << 19);  // lvl*1024 rows * 512 B

    for (int c = 0; c < NCHUNK; ++c) {
      __syncthreads();  // previous chunk fully consumed
      {
        const char* gsrc = cb16b + lvlbase + ((size_t)c << 15);
        char* ldst = (char*)clds + wave * 8192;
        #pragma unroll
        for (int i = 0; i < 8; ++i) gload16(gsrc + soff[i], ldst + i * 1024);
      }
      __syncthreads();  // vmcnt(0) drain at barrier => staging visible

      #pragma unroll
      for (int nt = 0; nt < 4; ++nt) {
        const int code0 = c * 64 + nt * 16;
        const float e2v = e2_lds[code0 + col];  // fold -||e||^2/2 into acc init
        f4 acc0 = {e2v, e2v, e2v, e2v};
        f4 acc1 = acc0;
        const char* bptr = (const char*)clds + (nt * 16 + col) * 512;
        #pragma unroll
        for (int kk = 0; kk < 8; ++kk) {
          h8 b = *(const h8*)(bptr + rdoff[kk]);
          acc0 = __builtin_amdgcn_mfma_f32_16x16x32_f16(af[0][kk], b, acc0, 0, 0, 0);
          acc1 = __builtin_amdgcn_mfma_f32_16x16x32_f16(af[1][kk], b, acc1, 0, 0, 0);
        }
        // pack (sortable(score) & ~1023) | (1023-code): umax == argmax with
        // argmin-style smaller-index tie-break
        const u32 invc = (u32)(code0 + col) ^ 1023u;
        #pragma unroll
        for (int i = 0; i < 4; ++i) {
          u32 u0 = __float_as_uint(acc0[i]);
          u32 s0 = u0 ^ (((u32)((int)u0 >> 31)) | 0x80000000u);
          u32 p0 = (s0 & 0xFFFFFC00u) | invc;
          if (p0 > best[0][i]) best[0][i] = p0;
          u32 u1 = __float_as_uint(acc1[i]);
          u32 s1 = u1 ^ (((u32)((int)u1 >> 31)) | 0x80000000u);
          u32 p1 = (s1 & 0xFFFFFC00u) | invc;
          if (p1 > best[1][i]) best[1][i] = p1;
        }
      }
    }

    // reduce best across the 16 column lanes (codes)
    #pragma unroll
    for (int mt = 0; mt < 2; ++mt)
      #pragma unroll
      for (int i = 0; i < 4; ++i) {
        u32 b = best[mt][i];
        #pragma unroll
        for (int off = 1; off < 16; off <<= 1) {
          u32 o = __shfl_xor(b, off, 16);
          if (o > b) b = o;
        }
        best[mt][i] = b;
      }

    if (col == 0) {
      #pragma unroll
      for (int mt = 0; mt < 2; ++mt)
        #pragma unroll
        for (int i = 0; i < 4; ++i) {
          const u32 p = best[mt][i];
          const int code = (int)((p & 1023u) ^ 1023u);
          const int t = wave * 32 + mt * 16 + quad * 4 + i;
          idx_hist[t][lvl] = code;
          const u32 s = p & 0xFFFFFC00u;
          const u32 u = (s & 0x80000000u) ? (s ^ 0x80000000u) : ~s;
          // dist = ||r||^2 - 2*(r.e - ||e||^2/2)
          commit_acc += r2_sh[t] - 2.0f * __uint_as_float(u);
        }
    }
    __syncthreads();  // idx_hist visible; clds/e2/r2 free

    if (lvl < LEVELS - 1) {  // fp16 residual update + next-level r2
      r2p[0] = 0.f; r2p[1] = 0.f;
      #pragma unroll
      for (int mt = 0; mt < 2; ++mt) {
        const int qidx = idx_hist[wave * 32 + mt * 16 + col][lvl];
        const _Float16* qr = cb16 + (((size_t)lvl << 10) + qidx) * DIM + quad * 8;
        #pragma unroll
        for (int kk = 0; kk < 8; ++kk) {
          h8 q = *(const h8*)(qr + kk * 32);
          h8 r = af[mt][kk] - q;
          af[mt][kk] = r;
          #pragma unroll
          for (int j = 0; j < 8; ++j) { float v = (float)r[j]; r2p[mt] += v * v; }
        }
      }
    }
  }

  // ---- epilogue: y = sum_l q_l, fp32-exact, fully coalesced (1KB/instr) ----
  float* yblk = out + (size_t)blockIdx.x * (TOKB * DIM);
  #pragma unroll 4
  for (int it = 0; it < 32; ++it) {
    const int f = it * 1024 + tid * 4;
    const int t = f >> 8;          // wave-uniform token -> scalar idx loads
    const int d = f & 255;
    const int4 qi = *(const int4*)&idx_hist[t][0];
    f4 q0 = *(const f4*)(cb32 + (size_t)qi.x * DIM + d);
    f4 q1 = *(const f4*)(cb32 + (size_t)(1024 + qi.y) * DIM + d);
    f4 q2 = *(const f4*)(cb32 + (size_t)(2048 + qi.z) * DIM + d);
    f4 q3 = *(const f4*)(cb32 + (size_t)(3072 + qi.w) * DIM + d);
    f4 y = (q0 + q1) + (q2 + q3);
    *(f4*)(yblk + f) = y;
  }

  // ---- commit: butterfly + one atomic per block ----
  #pragma unroll
  for (int off = 1; off < 64; off <<= 1) commit_acc += __shfl_xor(commit_acc, off, 64);
  if (lane == 0) csum_sh[wave] = commit_acc;
  __syncthreads();
  if (tid == 0) {
    const float tot = csum_sh[0] + csum_sh[1] + csum_sh[2] + csum_sh[3];
    atomicAdd(out + NELEM, tot * (0.25f / 16777216.0f));  // BETA / (N*D)
  }
}

extern "C" void kernel_launch(void* const* d_in, const int* in_sizes, int n_in,
                              void* d_out, int out_size, void* d_ws, size_t ws_size,
                              hipStream_t stream) {
  const float* x = (const float*)d_in[0];
  const float* cb = (const float*)d_in[1];
  float* out = (float*)d_out;
  _Float16* cb16 = (_Float16*)d_ws;  // 2 MiB
  float* e2h = (float*)((char*)d_ws + (size_t)LEVELS * KCODES * DIM * sizeof(_Float16));

  rvq_prep<<<(LEVELS * KCODES) / 4, 256, 0, stream>>>(cb, cb16, e2h);
  hipMemsetAsync(out + NELEM, 0, sizeof(float), stream);
  rvq_main<<<NTOK / TOKB, 256, 0, stream>>>(x, cb, cb16, e2h, out);
}

// Round 3
// 248.695 us; speedup vs baseline: 3.3398x; 1.0164x over previous
//
#include <hip/hip_runtime.h>

#define DIM 256
#define KCODES 1024
#define LEVELS 4
#define CHUNK 64
#define NCHUNK 16
#define TOKB 128                 // tokens per block (4 waves x 32)
#define NTOK 65536
#define NELEM (NTOK * DIM)

typedef _Float16 h8 __attribute__((ext_vector_type(8)));
typedef _Float16 h4 __attribute__((ext_vector_type(4)));
typedef _Float16 h2 __attribute__((ext_vector_type(2)));
typedef float f4 __attribute__((ext_vector_type(4)));
typedef unsigned int u32;

__device__ __forceinline__ void gload16(const void* g, void* l) {
  __builtin_amdgcn_global_load_lds(
      (const __attribute__((address_space(1))) void*)g,
      (__attribute__((address_space(3))) void*)l, 16, 0, 0);
}

// r2 accumulate over an h8 (v_dot2_f32_f16 when available: 4 instr vs 16)
__device__ __forceinline__ float sq8(h8 r, float acc) {
#if __has_builtin(__builtin_amdgcn_fdot2)
  #pragma unroll
  for (int j = 0; j < 4; ++j) {
    h2 p = {r[2 * j], r[2 * j + 1]};
    acc = __builtin_amdgcn_fdot2(p, p, acc, false);
  }
#else
  #pragma unroll
  for (int j = 0; j < 8; ++j) { float v = (float)r[j]; acc += v * v; }
#endif
  return acc;
}

// Phase 0: cb fp32 -> fp16; e2p = 0.25 - 0.5*||e||^2 (the +0.25 shift keeps all
// MFMA scores positive so raw float bits are unsigned-order-monotone -> 2-op
// argmax tracker). Also zeroes the commit accumulator (out is re-poisoned by
// the harness before every call).
__global__ __launch_bounds__(256) void rvq_prep(const float* __restrict__ cb,
                                                _Float16* __restrict__ cb16,
                                                float* __restrict__ e2p,
                                                float* __restrict__ out) {
  if (blockIdx.x == 0 && threadIdx.x == 0) out[NELEM] = 0.0f;
  const int row = blockIdx.x * 4 + (threadIdx.x >> 6);
  const int lane = threadIdx.x & 63;
  const float* src = cb + (size_t)row * DIM + lane * 4;
  f4 v = *(const f4*)src;
  h4 hv;
  hv[0] = (_Float16)v[0]; hv[1] = (_Float16)v[1];
  hv[2] = (_Float16)v[2]; hv[3] = (_Float16)v[3];
  *(h4*)(cb16 + (size_t)row * DIM + lane * 4) = hv;
  float s = v[0]*v[0] + v[1]*v[1] + v[2]*v[2] + v[3]*v[3];
  #pragma unroll
  for (int off = 32; off; off >>= 1) s += __shfl_xor(s, off, 64);
  if (lane == 0) e2p[row] = 0.25f - 0.5f * s;
}

// Main fused RVQ. Block = 4 waves; wave owns 32 tokens (2 m-tiles).
// Residual lives only as fp16 A-frags. LDS codebook chunks are DOUBLE-
// BUFFERED: one barrier per chunk; the global_load_lds for chunk g+1 is
// issued right after the barrier and drains at the NEXT barrier (a full
// compute phase later) -> no vmcnt stall. Chunks are contiguous across
// levels in cb16, so the prefetch also covers level boundaries.
__global__ __launch_bounds__(256, 2) void rvq_main(
    const float* __restrict__ x, const float* __restrict__ cb32,
    const _Float16* __restrict__ cb16, const float* __restrict__ e2p,
    float* __restrict__ out) {
  __shared__ __attribute__((aligned(16))) _Float16 clds[2][CHUNK * DIM];  // 64 KB
  __shared__ float e2_lds[KCODES];                                        // 4 KB
  __shared__ __attribute__((aligned(16))) int idx_hist[TOKB][4];          // 2 KB
  __shared__ float r2_sh[TOKB];
  __shared__ float csum_sh[4];

  const int tid = threadIdx.x;
  const int wave = tid >> 6, lane = tid & 63;
  const int col = lane & 15, quad = lane >> 4;
  const int Llo = lane & 31, Lhi = lane >> 5;

  // staging: call i -> rows (wave*16+2i, +1); lane L fills row position p=Llo
  // with global granule g = p ^ (row&7) (XOR swizzle, self-inverse).
  int soff[8], rdoff[8];
  #pragma unroll
  for (int i = 0; i < 8; ++i) {
    const int rl = wave * 16 + 2 * i + Lhi;
    soff[i] = rl * 512 + ((Llo ^ (rl & 7)) << 4);
  }
  #pragma unroll
  for (int kk = 0; kk < 8; ++kk)
    rdoff[kk] = (((kk * 4 + quad) ^ (col & 7)) << 4);

  const char* cb16b = (const char*)cb16;
  // issue chunk 0 staging immediately; it flies during the x-init loads
  {
    char* ldst = (char*)&clds[0][0] + wave * 8192;
    #pragma unroll
    for (int i = 0; i < 8; ++i) gload16(cb16b + soff[i], ldst + i * 1024);
  }

  // ---- init: x -> fp16 A-frags + r2 partials ----
  h8 af[2][8];
  float r2p[2] = {0.f, 0.f};
  const size_t tok0 = (size_t)blockIdx.x * TOKB + wave * 32;
  #pragma unroll
  for (int mt = 0; mt < 2; ++mt) {
    const float* xr = x + (tok0 + mt * 16 + col) * DIM + quad * 8;
    #pragma unroll
    for (int kk = 0; kk < 8; ++kk) {
      f4 a = *(const f4*)(xr + kk * 32);
      f4 b = *(const f4*)(xr + kk * 32 + 4);
      h8 h;
      #pragma unroll
      for (int j = 0; j < 4; ++j) { h[j] = (_Float16)a[j]; h[4 + j] = (_Float16)b[j]; }
      af[mt][kk] = h;
      r2p[mt] = sq8(h, r2p[mt]);
    }
  }

  float commit_acc = 0.f;

  for (int lvl = 0; lvl < LEVELS; ++lvl) {
    // pre-update residual norms -> LDS (wave-local slots; commit identity)
    #pragma unroll
    for (int mt = 0; mt < 2; ++mt) {
      float s = r2p[mt];
      s += __shfl_xor(s, 16, 64);
      s += __shfl_xor(s, 32, 64);
      if (quad == 0) r2_sh[wave * 32 + mt * 16 + col] = s;
    }
    // this level's shifted-e2 table (prev level's readers done: post-idx barrier)
    *(f4*)&e2_lds[tid * 4] = *(const f4*)(e2p + (lvl << 10) + tid * 4);

    u32 best[2][4];
    #pragma unroll
    for (int mt = 0; mt < 2; ++mt)
      #pragma unroll
      for (int i = 0; i < 4; ++i) best[mt][i] = 0u;

    for (int c = 0; c < NCHUNK; ++c) {
      __syncthreads();  // staging of chunk g (issued a full phase ago) visible
      {
        // prefetch chunk g+1 into the other buffer (contiguous across levels;
        // clamp keeps the last iteration in-bounds, write is harmless)
        const int gn = lvl * NCHUNK + c + 1;
        const char* gsrc = cb16b + ((size_t)(gn < 64 ? gn : 63) << 15);
        char* ldst = (char*)&clds[(c + 1) & 1][0] + wave * 8192;
        #pragma unroll
        for (int i = 0; i < 8; ++i) gload16(gsrc + soff[i], ldst + i * 1024);
      }

      const char* cbuf = (const char*)&clds[c & 1][0];
      #pragma unroll
      for (int nt = 0; nt < 4; ++nt) {
        const int code0 = c * 64 + nt * 16;
        const float e2v = e2_lds[code0 + col];  // 0.25 - ||e||^2/2
        f4 acc0 = {e2v, e2v, e2v, e2v};
        f4 acc1 = acc0;
        const char* bptr = cbuf + (nt * 16 + col) * 512;
        #pragma unroll
        for (int kk = 0; kk < 8; ++kk) {
          h8 b = *(const h8*)(bptr + rdoff[kk]);
          acc0 = __builtin_amdgcn_mfma_f32_16x16x32_f16(af[0][kk], b, acc0, 0, 0, 0);
          acc1 = __builtin_amdgcn_mfma_f32_16x16x32_f16(af[1][kk], b, acc1, 0, 0, 0);
        }
        // scores all positive -> raw bits unsigned-monotone; pack
        // (bits & ~1023) | (1023-code): umax == argmax, smaller-index ties
        const u32 invc = (u32)(code0 + col) ^ 1023u;
        #pragma unroll
        for (int i = 0; i < 4; ++i) {
          u32 p0 = (__float_as_uint(acc0[i]) & 0xFFFFFC00u) | invc;
          if (p0 > best[0][i]) best[0][i] = p0;
          u32 p1 = (__float_as_uint(acc1[i]) & 0xFFFFFC00u) | invc;
          if (p1 > best[1][i]) best[1][i] = p1;
        }
      }
    }

    // reduce best across the 16 column lanes
    #pragma unroll
    for (int mt = 0; mt < 2; ++mt)
      #pragma unroll
      for (int i = 0; i < 4; ++i) {
        u32 b = best[mt][i];
        #pragma unroll
        for (int off = 1; off < 16; off <<= 1) {
          u32 o = __shfl_xor(b, off, 16);
          if (o > b) b = o;
        }
        best[mt][i] = b;
      }

    if (col == 0) {
      #pragma unroll
      for (int mt = 0; mt < 2; ++mt)
        #pragma unroll
        for (int i = 0; i < 4; ++i) {
          const u32 p = best[mt][i];
          const int code = (int)((p & 1023u) ^ 1023u);
          const int t = wave * 32 + mt * 16 + quad * 4 + i;
          idx_hist[t][lvl] = code;
          const float sc = __uint_as_float(p & 0xFFFFFC00u) - 0.25f;  // r.e - e^2/2
          commit_acc += r2_sh[t] - 2.0f * sc;  // dist = ||r||^2 - 2*sc
        }
    }
    __syncthreads();  // idx_hist visible to all; e2_lds free for next level

    if (lvl < LEVELS - 1) {  // fp16 residual update + next-level r2
      r2p[0] = 0.f; r2p[1] = 0.f;
      #pragma unroll
      for (int mt = 0; mt < 2; ++mt) {
        const int qidx = idx_hist[wave * 32 + mt * 16 + col][lvl];
        const _Float16* qr = cb16 + (((size_t)lvl << 10) + qidx) * DIM + quad * 8;
        #pragma unroll
        for (int kk = 0; kk < 8; ++kk) {
          h8 q = *(const h8*)(qr + kk * 32);
          h8 r = af[mt][kk] - q;
          af[mt][kk] = r;
          r2p[mt] = sq8(r, r2p[mt]);
        }
      }
    }
  }

  // ---- epilogue: y = sum_l q_l, fp32-exact, fully coalesced ----
  float* yblk = out + (size_t)blockIdx.x * (TOKB * DIM);
  #pragma unroll 4
  for (int it = 0; it < 32; ++it) {
    const int f = it * 1024 + tid * 4;
    const int t = f >> 8;  // wave-uniform token
    const int d = f & 255;
    const int4 qi = *(const int4*)&idx_hist[t][0];
    f4 q0 = *(const f4*)(cb32 + (size_t)qi.x * DIM + d);
    f4 q1 = *(const f4*)(cb32 + (size_t)(1024 + qi.y) * DIM + d);
    f4 q2 = *(const f4*)(cb32 + (size_t)(2048 + qi.z) * DIM + d);
    f4 q3 = *(const f4*)(cb32 + (size_t)(3072 + qi.w) * DIM + d);
    f4 y = (q0 + q1) + (q2 + q3);
    *(f4*)(yblk + f) = y;
  }

  // ---- commit: butterfly + one atomic per block ----
  #pragma unroll
  for (int off = 1; off < 64; off <<= 1) commit_acc += __shfl_xor(commit_acc, off, 64);
  if (lane == 0) csum_sh[wave] = commit_acc;
  __syncthreads();
  if (tid == 0) {
    const float tot = csum_sh[0] + csum_sh[1] + csum_sh[2] + csum_sh[3];
    atomicAdd(out + NELEM, tot * (0.25f / 16777216.0f));  // BETA / (N*D)
  }
}

extern "C" void kernel_launch(void* const* d_in, const int* in_sizes, int n_in,
                              void* d_out, int out_size, void* d_ws, size_t ws_size,
                              hipStream_t stream) {
  const float* x = (const float*)d_in[0];
  const float* cb = (const float*)d_in[1];
  float* out = (float*)d_out;
  _Float16* cb16 = (_Float16*)d_ws;  // 2 MiB
  float* e2p = (float*)((char*)d_ws + (size_t)LEVELS * KCODES * DIM * sizeof(_Float16));

  rvq_prep<<<(LEVELS * KCODES) / 4, 256, 0, stream>>>(cb, cb16, e2p, out);
  rvq_main<<<NTOK / TOKB, 256, 0, stream>>>(x, cb, cb16, e2p, out);
}